// Round 7
// baseline (127.863 us; speedup 1.0000x reference)
//
#include <hip/hip_runtime.h>

// ShiftedPatchTokenization on MI355X (gfx950)
// x[64,3,224,224] f32 -> out[64,196,768] f32
// fold_w (+G/Bt partials) -> gb reduce -> pack (vec4) -> 224x192 half-K
// software-pipelined MFMA GEMM (fat 112x96 waves, 1 barrier/tile).

typedef short bf16x8 __attribute__((ext_vector_type(8)));
typedef unsigned short u16x8 __attribute__((ext_vector_type(8)));
typedef float f32x4 __attribute__((ext_vector_type(4)));

#define GLOBAL_AS __attribute__((address_space(1)))
#define LDS_AS __attribute__((address_space(3)))

__device__ __forceinline__ unsigned short f2bf(float f) {
  union { float f; unsigned int u; } v;
  v.f = f;
  unsigned int u = v.u;
  unsigned int r = (u + 0x7FFFu + ((u >> 16) & 1u)) >> 16;  // RNE
  return (unsigned short)r;
}

// ---------------------------------------------------------------------------
// Kernel 1: fold gamma*w over duplicated shift groups -> w2t[768][2304] bf16,
// plus per-f2-block partial sums. grid (144, 3), block 256
// ---------------------------------------------------------------------------
__global__ __launch_bounds__(256) void spt_fold_w(
    const float* __restrict__ gamma, const float* __restrict__ beta,
    const float* __restrict__ w, unsigned short* __restrict__ w2t,
    float* __restrict__ Gp, float* __restrict__ Bp)
{
  __shared__ float tile[16][257];
  const int f2blk = blockIdx.x * 16;
  const int jblk  = blockIdx.y * 256;
  const int t = threadIdx.x;
  const int j = jblk + t;
  float gacc = 0.f, bacc = 0.f;
  #pragma unroll
  for (int i = 0; i < 16; ++i) {
    const int f2 = f2blk + i;
    const int g = f2 / 768;
    const int rem = f2 % 768;  // c*256 + p1*16 + p2
    float v, bv;
    if (g == 0) {
      const int f = rem;
      const float wv = w[(size_t)f * 768 + j];
      v = gamma[f] * wv;
      bv = beta[f] * wv;
    } else if (g == 1) {
      const int fa = 768 + rem, fb = 2304 + rem;   // left_up, left_down
      const float wa = w[(size_t)fa * 768 + j], wb = w[(size_t)fb * 768 + j];
      v = gamma[fa] * wa + gamma[fb] * wb;
      bv = beta[fa] * wa + beta[fb] * wb;
    } else {
      const int fa = 1536 + rem, fb = 3072 + rem;  // right_up, right_down
      const float wa = w[(size_t)fa * 768 + j], wb = w[(size_t)fb * 768 + j];
      v = gamma[fa] * wa + gamma[fb] * wb;
      bv = beta[fa] * wa + beta[fb] * wb;
    }
    tile[i][t] = v;
    gacc += v;
    bacc += bv;
  }
  __syncthreads();
  u16x8 lo, hi;
  #pragma unroll
  for (int i = 0; i < 8; ++i) {
    lo[i] = f2bf(tile[i][t]);
    hi[i] = f2bf(tile[8 + i][t]);
  }
  unsigned short* dst = w2t + (size_t)j * 2304 + f2blk;
  *(u16x8*)dst = lo;
  *(u16x8*)(dst + 8) = hi;
  Gp[blockIdx.x * 768 + j] = gacc;
  Bp[blockIdx.x * 768 + j] = bacc;
}

// ---------------------------------------------------------------------------
// Kernel 2: reduce 144 partials -> G[768], Bt[768] (+b). grid 3, block 256
// ---------------------------------------------------------------------------
__global__ __launch_bounds__(256) void spt_gb(
    const float* __restrict__ Gp, const float* __restrict__ Bp,
    const float* __restrict__ bvec, float* __restrict__ G, float* __restrict__ Bt)
{
  const int j = blockIdx.x * 256 + threadIdx.x;
  float g = 0.f, bb = 0.f;
  for (int i = 0; i < 144; ++i) {
    g += Gp[i * 768 + j];
    bb += Bp[i * 768 + j];
  }
  G[j] = g;
  Bt[j] = bb + bvec[j];
}

// ---------------------------------------------------------------------------
// Kernel 3: pack V[12544][2304] bf16 + per-token LN stats (r, -mu*r)
// grid 896, block 256
// ---------------------------------------------------------------------------
__global__ __launch_bounds__(256) void spt_pack(
    const float* __restrict__ x, unsigned short* __restrict__ V,
    float2* __restrict__ stats)
{
  __shared__ unsigned short slab[14 * 2312];  // token-major, +8 pad per row
  __shared__ float sred[4][224];
  __shared__ float qred[4][224];
  const int bi = blockIdx.x;
  const int b = bi / 14, hi = bi % 14;
  const int t = threadIdx.x;
  const float TW = 16.0f / 224.0f;

  const int q = t % 56;
  const int grp = t / 56;
  const int x4 = q * 4;

  int sloff[4];
  {
    int wi = x4 % 14, p2 = x4 / 14;
    #pragma unroll
    for (int j = 0; j < 4; ++j) {
      sloff[j] = wi * 2312 + p2;
      if (++wi == 14) { wi = 0; ++p2; }
    }
  }

  if (t < 224) {
    f32x4 sAcc = {0.f, 0.f, 0.f, 0.f}, qAcc = {0.f, 0.f, 0.f, 0.f};
    #pragma unroll
    for (int it = 0; it < 12; ++it) {
      const int cp = grp * 12 + it;
      const int c = cp >> 4, p1 = cp & 15;
      const int y = p1 * 14 + hi;
      const float* row = x + ((size_t)(b * 3 + c)) * 50176 + (size_t)y * 224;
      const f32x4 xv = *(const f32x4*)(row + x4);
      f32x4 ra = {0.f,0.f,0.f,0.f}, rb = {0.f,0.f,0.f,0.f};
      f32x4 la = {0.f,0.f,0.f,0.f}, lb = {0.f,0.f,0.f,0.f};
      if (q < 54) {
        ra = *(const f32x4*)(row + x4 + 8);
        if (y < 223) rb = *(const f32x4*)(row + x4 + 8 + 224);
      }
      if (q >= 2) {
        la = *(const f32x4*)(row + x4 - 8);
        if (y > 0) lb = *(const f32x4*)(row + x4 - 8 - 224);
      }
      const f32x4 rv = (1.0f - TW) * ra + TW * rb;
      const f32x4 lv = (1.0f - TW) * la + TW * lb;
      sAcc += xv + 2.0f * (lv + rv);
      qAcc += xv * xv + 2.0f * (lv * lv + rv * rv);
      const int kb = c * 256 + p1 * 16;
      #pragma unroll
      for (int j = 0; j < 4; ++j) {
        slab[sloff[j] + kb]        = f2bf(xv[j]);
        slab[sloff[j] + kb + 768]  = f2bf(lv[j]);
        slab[sloff[j] + kb + 1536] = f2bf(rv[j]);
      }
    }
    #pragma unroll
    for (int j = 0; j < 4; ++j) {
      sred[grp][x4 + j] = sAcc[j];
      qred[grp][x4 + j] = qAcc[j];
    }
  }
  __syncthreads();

  float ss = 0.f, qq = 0.f;
  if (t < 224) {
    ss = sred[0][t] + sred[1][t] + sred[2][t] + sred[3][t];
    qq = qred[0][t] + qred[1][t] + qred[2][t] + qred[3][t];
  }
  __syncthreads();
  if (t < 224) { sred[0][t] = ss; qred[0][t] = qq; }
  __syncthreads();

  const int tok0 = b * 196 + hi * 14;
  if (t < 14) {
    float S = 0.f, Q = 0.f;
    #pragma unroll
    for (int p = 0; p < 16; ++p) { S += sred[0][t + 14 * p]; Q += qred[0][t + 14 * p]; }
    const float mu = S / 3840.f;
    const float var = Q / 3840.f - mu * mu;
    const float r = rsqrtf(var + 1e-5f);
    stats[tok0 + t] = make_float2(r, -mu * r);
  }

  if (t < 224) {
    const int wi2 = t >> 4, sub = t & 15;
    const size_t vbase = (size_t)(tok0 + wi2) * 2304;
    #pragma unroll
    for (int cc = 0; cc < 18; ++cc) {
      const int off8 = (cc * 16 + sub) * 8;
      *(u16x8*)&V[vbase + off8] = *(const u16x8*)&slab[wi2 * 2312 + off8];
    }
  }
}

// ---------------------------------------------------------------------------
// Kernel 4: GEMM  out[m][j] = r_m * (V[m,:] . w2t[j,:]) + (-mu*r)_m * G[j] + Bt[j]
// 224x192 tile, BK=64, 4 waves (2x2, wave=112x96, 7x6 frags -> 0.31 LDS
// reads/MFMA). Half-K software pipeline: read h1(kt) under MFMA h0(kt);
// drain(lgkm+vm)+barrier; restage(kt+2); read h0(kt+1) under MFMA h1(kt).
// One barrier + one vmcnt(0) per K-step (waited loads issued a full step
// earlier). 104 KiB LDS dbuf, 1 block/CU, 1 wave/SIMD (VGPR budget 512).
// XOR swizzle (byte ^= (row&7)<<4) w/ pre-swizzled source. grid 224 = 56m x 4n,
// exact XCD chunking (28/XCD), N-fastest.
// ---------------------------------------------------------------------------
__global__ __launch_bounds__(256, 1) void spt_gemm(
    const unsigned short* __restrict__ V, const unsigned short* __restrict__ w2t,
    const float2* __restrict__ stats, const float* __restrict__ G,
    const float* __restrict__ Bt, float* __restrict__ out)
{
  __shared__ unsigned short Alds[2][224 * 64];
  __shared__ unsigned short Blds[2][192 * 64];

  const int orig = blockIdx.x;
  const int wgid = (orig & 7) * 28 + (orig >> 3);  // exact: 224 = 8 * 28
  const int m0 = (wgid >> 2) * 224;
  const int n0 = (wgid & 3) * 192;
  const int t = threadIdx.x;
  const int w = t >> 6, l = t & 63;
  const int wr = w >> 1;   // 0..1 -> 112-row half
  const int wn = w & 1;    // 0..1 -> 96-col half

  f32x4 acc[7][6] = {};
  bf16x8 fXA[7], fXB[6], fYA[7], fYB[6];

  // Staging: chunk c = i*256 + t -> row c>>3, 16B piece c&7; source
  // pre-swizzled so linear LDS dest + swizzled read agree.
#define STAGE(pb, kt)                                                          \
  {                                                                            \
    const int k0s = (kt) << 6;                                                 \
    _Pragma("unroll") for (int i = 0; i < 7; ++i) {                            \
      const int c = i * 256 + t;                                               \
      const int row = c >> 3;                                                  \
      const int srcel = (((c & 7) ^ (row & 7)) << 3);                          \
      const unsigned short* ga = V + (size_t)(m0 + row) * 2304 + k0s + srcel;  \
      __builtin_amdgcn_global_load_lds((const GLOBAL_AS unsigned int*)ga,      \
          (LDS_AS unsigned int*)&Alds[pb][c * 8], 16, 0, 0);                   \
    }                                                                          \
    _Pragma("unroll") for (int i = 0; i < 6; ++i) {                            \
      const int c = i * 256 + t;                                               \
      const int row = c >> 3;                                                  \
      const int srcel = (((c & 7) ^ (row & 7)) << 3);                          \
      const unsigned short* gb = w2t + (size_t)(n0 + row) * 2304 + k0s + srcel;\
      __builtin_amdgcn_global_load_lds((const GLOBAL_AS unsigned int*)gb,      \
          (LDS_AS unsigned int*)&Blds[pb][c * 8], 16, 0, 0);                   \
    }                                                                          \
  }

  // Read one half-K's 13 fragments into a named group.
#define READF(FA, FB, pb, kkb)                                                 \
  {                                                                            \
    const int lane15 = l & 15;                                                 \
    const int kb = (kkb) + ((l >> 4) << 4);                                    \
    _Pragma("unroll") for (int n = 0; n < 6; ++n) {                            \
      const int row = wn * 96 + n * 16 + lane15;                               \
      const int phys = row * 128 + (kb ^ ((row & 7) << 4));                    \
      FB[n] = *(const bf16x8*)&Blds[pb][phys >> 1];                            \
    }                                                                          \
    _Pragma("unroll") for (int m = 0; m < 7; ++m) {                            \
      const int row = wr * 112 + m * 16 + lane15;                              \
      const int phys = row * 128 + (kb ^ ((row & 7) << 4));                    \
      FA[m] = *(const bf16x8*)&Alds[pb][phys >> 1];                            \
    }                                                                          \
  }

#define MF(FA, FB)                                                             \
  _Pragma("unroll") for (int m = 0; m < 7; ++m)                                \
    _Pragma("unroll") for (int n = 0; n < 6; ++n)                              \
      acc[m][n] = __builtin_amdgcn_mfma_f32_16x16x32_bf16(FA[m], FB[n],        \
                                                          acc[m][n], 0, 0, 0);

  STAGE(0, 0);
  STAGE(1, 1);
  asm volatile("s_waitcnt vmcnt(13)" ::: "memory");  // tile 0 landed
  asm volatile("s_barrier" ::: "memory");
  READF(fXA, fXB, 0, 0);                             // h0(0)

  for (int kt = 0; kt < 36; ++kt) {
    const int pb = kt & 1;
    READF(fYA, fYB, pb, 64);                         // h1(kt), overlaps:
    MF(fXA, fXB);                                    //   MFMA h0(kt)
    // drain my LDS reads + all my staged loads (issued a full step ago),
    // then barrier: buf[pb] free for restage, tile kt+1 certified for all.
    asm volatile("s_waitcnt lgkmcnt(0) vmcnt(0)\n\ts_barrier" ::: "memory");
    if (kt < 34) STAGE(pb, kt + 2);
    if (kt < 35) READF(fXA, fXB, pb ^ 1, 0);         // h0(kt+1), overlaps:
    MF(fYA, fYB);                                    //   MFMA h1(kt)
  }

  // Epilogue: C/D frag layout col = l&15, row = (l>>4)*4 + reg
  const int lane15 = l & 15;
  const int lg = (l >> 4) * 4;
  #pragma unroll
  for (int m = 0; m < 7; ++m) {
    const int rowb = m0 + wr * 112 + m * 16 + lg;
    float2 st[4];
    #pragma unroll
    for (int r = 0; r < 4; ++r) st[r] = stats[rowb + r];
    #pragma unroll
    for (int n = 0; n < 6; ++n) {
      const int col = n0 + wn * 96 + n * 16 + lane15;
      const float Gc = G[col];
      const float Bc = Bt[col];
      #pragma unroll
      for (int r = 0; r < 4; ++r) {
        out[(size_t)(rowb + r) * 768 + col] = st[r].x * acc[m][n][r] + st[r].y * Gc + Bc;
      }
    }
  }
#undef STAGE
#undef READF
#undef MF
}

// ---------------------------------------------------------------------------
// Workspace layout (bytes):
//   V     : 0            57,802,752
//   w2t   : 57,802,752    3,538,944
//   stats : 61,341,696      100,352
//   G     : 61,442,048        3,072
//   Bt    : 61,445,120        3,072
//   Gp    : 61,448,192      442,368
//   Bp    : 61,890,560      442,368   -> total 62,332,928
// ---------------------------------------------------------------------------
extern "C" void kernel_launch(void* const* d_in, const int* in_sizes, int n_in,
                              void* d_out, int out_size, void* d_ws, size_t ws_size,
                              hipStream_t stream) {
  const float* x     = (const float*)d_in[0];
  const float* gamma = (const float*)d_in[1];
  const float* beta  = (const float*)d_in[2];
  const float* w     = (const float*)d_in[3];
  const float* bvec  = (const float*)d_in[4];
  float* out = (float*)d_out;

  char* ws = (char*)d_ws;
  unsigned short* V   = (unsigned short*)(ws);
  unsigned short* w2t = (unsigned short*)(ws + 57802752);
  float2* stats       = (float2*)(ws + 61341696);
  float* G            = (float*)(ws + 61442048);
  float* Bt           = (float*)(ws + 61445120);
  float* Gp           = (float*)(ws + 61448192);
  float* Bp           = (float*)(ws + 61890560);

  spt_pack<<<896, 256, 0, stream>>>(x, V, stats);
  spt_fold_w<<<dim3(144, 3), 256, 0, stream>>>(gamma, beta, w, w2t, Gp, Bp);
  spt_gb<<<3, 256, 0, stream>>>(Gp, Bp, bvec, G, Bt);
  spt_gemm<<<224, 256, 0, stream>>>(V, w2t, stats, G, Bt, out);
}

// Round 8
// 107.374 us; speedup vs baseline: 1.1908x; 1.1908x over previous
//
#include <hip/hip_runtime.h>

// ShiftedPatchTokenization on MI355X (gfx950)
// x[64,3,224,224] f32 -> out[64,196,768] f32
// fold_w (+G/Bt partials) -> gb reduce -> pack (vec4) -> 224x192 triple-buffered
// fat-wave (112x96) MFMA GEMM, 2-step prefetch depth, 1 barrier/K-step.

typedef short bf16x8 __attribute__((ext_vector_type(8)));
typedef unsigned short u16x8 __attribute__((ext_vector_type(8)));
typedef float f32x4 __attribute__((ext_vector_type(4)));

#define GLOBAL_AS __attribute__((address_space(1)))
#define LDS_AS __attribute__((address_space(3)))

__device__ __forceinline__ unsigned short f2bf(float f) {
  union { float f; unsigned int u; } v;
  v.f = f;
  unsigned int u = v.u;
  unsigned int r = (u + 0x7FFFu + ((u >> 16) & 1u)) >> 16;  // RNE
  return (unsigned short)r;
}

// ---------------------------------------------------------------------------
// Kernel 1: fold gamma*w over duplicated shift groups -> w2t[768][2304] bf16,
// plus per-f2-block partial sums. grid (144, 3), block 256
// ---------------------------------------------------------------------------
__global__ __launch_bounds__(256) void spt_fold_w(
    const float* __restrict__ gamma, const float* __restrict__ beta,
    const float* __restrict__ w, unsigned short* __restrict__ w2t,
    float* __restrict__ Gp, float* __restrict__ Bp)
{
  __shared__ float tile[16][257];
  const int f2blk = blockIdx.x * 16;
  const int jblk  = blockIdx.y * 256;
  const int t = threadIdx.x;
  const int j = jblk + t;
  float gacc = 0.f, bacc = 0.f;
  #pragma unroll
  for (int i = 0; i < 16; ++i) {
    const int f2 = f2blk + i;
    const int g = f2 / 768;
    const int rem = f2 % 768;  // c*256 + p1*16 + p2
    float v, bv;
    if (g == 0) {
      const int f = rem;
      const float wv = w[(size_t)f * 768 + j];
      v = gamma[f] * wv;
      bv = beta[f] * wv;
    } else if (g == 1) {
      const int fa = 768 + rem, fb = 2304 + rem;   // left_up, left_down
      const float wa = w[(size_t)fa * 768 + j], wb = w[(size_t)fb * 768 + j];
      v = gamma[fa] * wa + gamma[fb] * wb;
      bv = beta[fa] * wa + beta[fb] * wb;
    } else {
      const int fa = 1536 + rem, fb = 3072 + rem;  // right_up, right_down
      const float wa = w[(size_t)fa * 768 + j], wb = w[(size_t)fb * 768 + j];
      v = gamma[fa] * wa + gamma[fb] * wb;
      bv = beta[fa] * wa + beta[fb] * wb;
    }
    tile[i][t] = v;
    gacc += v;
    bacc += bv;
  }
  __syncthreads();
  u16x8 lo, hi;
  #pragma unroll
  for (int i = 0; i < 8; ++i) {
    lo[i] = f2bf(tile[i][t]);
    hi[i] = f2bf(tile[8 + i][t]);
  }
  unsigned short* dst = w2t + (size_t)j * 2304 + f2blk;
  *(u16x8*)dst = lo;
  *(u16x8*)(dst + 8) = hi;
  Gp[blockIdx.x * 768 + j] = gacc;
  Bp[blockIdx.x * 768 + j] = bacc;
}

// ---------------------------------------------------------------------------
// Kernel 2: reduce 144 partials -> G[768], Bt[768] (+b). grid 3, block 256
// ---------------------------------------------------------------------------
__global__ __launch_bounds__(256) void spt_gb(
    const float* __restrict__ Gp, const float* __restrict__ Bp,
    const float* __restrict__ bvec, float* __restrict__ G, float* __restrict__ Bt)
{
  const int j = blockIdx.x * 256 + threadIdx.x;
  float g = 0.f, bb = 0.f;
  for (int i = 0; i < 144; ++i) {
    g += Gp[i * 768 + j];
    bb += Bp[i * 768 + j];
  }
  G[j] = g;
  Bt[j] = bb + bvec[j];
}

// ---------------------------------------------------------------------------
// Kernel 3: pack V[12544][2304] bf16 + per-token LN stats (r, -mu*r)
// grid 896, block 256
// ---------------------------------------------------------------------------
__global__ __launch_bounds__(256) void spt_pack(
    const float* __restrict__ x, unsigned short* __restrict__ V,
    float2* __restrict__ stats)
{
  __shared__ unsigned short slab[14 * 2312];  // token-major, +8 pad per row
  __shared__ float sred[4][224];
  __shared__ float qred[4][224];
  const int bi = blockIdx.x;
  const int b = bi / 14, hi = bi % 14;
  const int t = threadIdx.x;
  const float TW = 16.0f / 224.0f;

  const int q = t % 56;
  const int grp = t / 56;
  const int x4 = q * 4;

  int sloff[4];
  {
    int wi = x4 % 14, p2 = x4 / 14;
    #pragma unroll
    for (int j = 0; j < 4; ++j) {
      sloff[j] = wi * 2312 + p2;
      if (++wi == 14) { wi = 0; ++p2; }
    }
  }

  if (t < 224) {
    f32x4 sAcc = {0.f, 0.f, 0.f, 0.f}, qAcc = {0.f, 0.f, 0.f, 0.f};
    #pragma unroll
    for (int it = 0; it < 12; ++it) {
      const int cp = grp * 12 + it;
      const int c = cp >> 4, p1 = cp & 15;
      const int y = p1 * 14 + hi;
      const float* row = x + ((size_t)(b * 3 + c)) * 50176 + (size_t)y * 224;
      const f32x4 xv = *(const f32x4*)(row + x4);
      f32x4 ra = {0.f,0.f,0.f,0.f}, rb = {0.f,0.f,0.f,0.f};
      f32x4 la = {0.f,0.f,0.f,0.f}, lb = {0.f,0.f,0.f,0.f};
      if (q < 54) {
        ra = *(const f32x4*)(row + x4 + 8);
        if (y < 223) rb = *(const f32x4*)(row + x4 + 8 + 224);
      }
      if (q >= 2) {
        la = *(const f32x4*)(row + x4 - 8);
        if (y > 0) lb = *(const f32x4*)(row + x4 - 8 - 224);
      }
      const f32x4 rv = (1.0f - TW) * ra + TW * rb;
      const f32x4 lv = (1.0f - TW) * la + TW * lb;
      sAcc += xv + 2.0f * (lv + rv);
      qAcc += xv * xv + 2.0f * (lv * lv + rv * rv);
      const int kb = c * 256 + p1 * 16;
      #pragma unroll
      for (int j = 0; j < 4; ++j) {
        slab[sloff[j] + kb]        = f2bf(xv[j]);
        slab[sloff[j] + kb + 768]  = f2bf(lv[j]);
        slab[sloff[j] + kb + 1536] = f2bf(rv[j]);
      }
    }
    #pragma unroll
    for (int j = 0; j < 4; ++j) {
      sred[grp][x4 + j] = sAcc[j];
      qred[grp][x4 + j] = qAcc[j];
    }
  }
  __syncthreads();

  float ss = 0.f, qq = 0.f;
  if (t < 224) {
    ss = sred[0][t] + sred[1][t] + sred[2][t] + sred[3][t];
    qq = qred[0][t] + qred[1][t] + qred[2][t] + qred[3][t];
  }
  __syncthreads();
  if (t < 224) { sred[0][t] = ss; qred[0][t] = qq; }
  __syncthreads();

  const int tok0 = b * 196 + hi * 14;
  if (t < 14) {
    float S = 0.f, Q = 0.f;
    #pragma unroll
    for (int p = 0; p < 16; ++p) { S += sred[0][t + 14 * p]; Q += qred[0][t + 14 * p]; }
    const float mu = S / 3840.f;
    const float var = Q / 3840.f - mu * mu;
    const float r = rsqrtf(var + 1e-5f);
    stats[tok0 + t] = make_float2(r, -mu * r);
  }

  if (t < 224) {
    const int wi2 = t >> 4, sub = t & 15;
    const size_t vbase = (size_t)(tok0 + wi2) * 2304;
    #pragma unroll
    for (int cc = 0; cc < 18; ++cc) {
      const int off8 = (cc * 16 + sub) * 8;
      *(u16x8*)&V[vbase + off8] = *(const u16x8*)&slab[wi2 * 2312 + off8];
    }
  }
}

// ---------------------------------------------------------------------------
// Kernel 4: GEMM  out[m][j] = r_m * (V[m,:] . w2t[j,:]) + (-mu*r)_m * G[j] + Bt[j]
// 224x192 tile, BK=64, 4 waves (2x2, wave=112x96, 7x6 frags, 51.7 FLOP/LDS-byte
// -> compute-bound geometry). TRIPLE-buffered LDS (156 KiB): phase kt reads
// buf P, certifies buf P+1 (vmcnt(13): those loads are 2 K-steps old ~3300cyc
// >> 900cyc HBM), restages P with tile kt+3. One barrier per K-step.
// Static buf indices via 3-phase unrolled rotation -> all ds_reads are
// base+imm (XOR swizzle term (row&7)=l&7 is lane-constant across m,n).
// grid 224 = 56m x 4n, exact XCD chunking (28/XCD), N-fastest.
// ---------------------------------------------------------------------------
__global__ __launch_bounds__(256, 1) void spt_gemm(
    const unsigned short* __restrict__ V, const unsigned short* __restrict__ w2t,
    const float2* __restrict__ stats, const float* __restrict__ G,
    const float* __restrict__ Bt, float* __restrict__ out)
{
  // per buf: A = 224*64 shorts (28672 B), then B = 192*64 shorts (24576 B)
  __shared__ unsigned short lds[3][26624];

  const int orig = blockIdx.x;
  const int wgid = (orig & 7) * 28 + (orig >> 3);  // exact: 224 = 8 * 28
  const int m0 = (wgid >> 2) * 224;
  const int n0 = (wgid & 3) * 192;
  const int t = threadIdx.x;
  const int w = t >> 6, l = t & 63;
  const int wr = w >> 1;   // 0..1 -> 112-row half
  const int wn = w & 1;    // 0..1 -> 96-col half

  f32x4 acc[7][6] = {};
  bf16x8 fXA[7], fXB[6], fYA[7], fYB[6];

  // ---- staging bases (per-thread, loop-invariant) ----
  // chunk c = i*256 + t -> row = i*32 + (t>>3), 16B piece (t&7);
  // source pre-swizzled: srcel = ((t&7) ^ ((t>>3)&7)) * 8 elems (same all i).
  const int srcel = (((t & 7) ^ ((t >> 3) & 7)) << 3);
  const int rbase = t >> 3;
  const unsigned short* gA[7];
  const unsigned short* gB[6];
  #pragma unroll
  for (int i = 0; i < 7; ++i) gA[i] = V   + (size_t)(m0 + i * 32 + rbase) * 2304 + srcel;
  #pragma unroll
  for (int i = 0; i < 6; ++i) gB[i] = w2t + (size_t)(n0 + i * 32 + rbase) * 2304 + srcel;

  // ---- read offsets (bytes, loop-invariant; m/n stride 2048) ----
  const int lane15 = l & 15;
  const int kcol = (l >> 4) << 4;
  const int sxz = (l & 7) << 4;                      // (row&7)<<4 == (l&7)<<4
  const int offAlo = (wr * 112 + lane15) * 128 + (kcol ^ sxz);
  const int offAhi = (wr * 112 + lane15) * 128 + ((64 + kcol) ^ sxz);
  const int offBlo = 28672 + (wn * 96 + lane15) * 128 + (kcol ^ sxz);
  const int offBhi = 28672 + (wn * 96 + lane15) * 128 + ((64 + kcol) ^ sxz);

#define STAGE(P, KS)                                                           \
  {                                                                            \
    _Pragma("unroll") for (int i = 0; i < 7; ++i)                              \
      __builtin_amdgcn_global_load_lds(                                        \
          (const GLOBAL_AS unsigned int*)(gA[i] + (KS)),                       \
          (LDS_AS unsigned int*)&lds[P][(i * 256 + t) * 8], 16, 0, 0);         \
    _Pragma("unroll") for (int i = 0; i < 6; ++i)                              \
      __builtin_amdgcn_global_load_lds(                                        \
          (const GLOBAL_AS unsigned int*)(gB[i] + (KS)),                       \
          (LDS_AS unsigned int*)&lds[P][14336 + (i * 256 + t) * 8], 16, 0, 0); \
  }

#define READF(FA, FB, P, OA, OB)                                               \
  {                                                                            \
    const char* bufc = (const char*)&lds[P][0];                                \
    _Pragma("unroll") for (int n = 0; n < 6; ++n)                              \
      FB[n] = *(const bf16x8*)(bufc + (OB) + n * 2048);                        \
    _Pragma("unroll") for (int m = 0; m < 7; ++m)                              \
      FA[m] = *(const bf16x8*)(bufc + (OA) + m * 2048);                        \
  }

#define MF(FA, FB)                                                             \
  _Pragma("unroll") for (int m = 0; m < 7; ++m)                                \
    _Pragma("unroll") for (int n = 0; n < 6; ++n)                              \
      acc[m][n] = __builtin_amdgcn_mfma_f32_16x16x32_bf16(FA[m], FB[n],        \
                                                          acc[m][n], 0, 0, 0);

  // PHASE(P, KS): buf P = tile kt certified, fX = (P, lo). Reads hi, MFMAs,
  // then 1 barrier: frees P (lgkm0) + certifies P+1 (own vm(13), 2 steps old).
#define PHASE(P, PN, KS3, VMN)                                                 \
  {                                                                            \
    READF(fYA, fYB, P, offAhi, offBhi);                                        \
    MF(fXA, fXB);                                                              \
    asm volatile("s_waitcnt vmcnt(" #VMN ") lgkmcnt(0)\n\ts_barrier" ::: "memory"); \
    STAGE(P, KS3);                                                             \
    READF(fXA, fXB, PN, offAlo, offBlo);                                       \
    MF(fYA, fYB);                                                              \
  }
#define PHASE_NS(P, PN, VMN)                                                   \
  {                                                                            \
    READF(fYA, fYB, P, offAhi, offBhi);                                        \
    MF(fXA, fXB);                                                              \
    asm volatile("s_waitcnt vmcnt(" #VMN ") lgkmcnt(0)\n\ts_barrier" ::: "memory"); \
    READF(fXA, fXB, PN, offAlo, offBlo);                                       \
    MF(fYA, fYB);                                                              \
  }

  STAGE(0, 0);
  STAGE(1, 64);
  STAGE(2, 128);
  asm volatile("s_waitcnt vmcnt(26)\n\ts_barrier" ::: "memory");  // tile0 landed
  READF(fXA, fXB, 0, offAlo, offBlo);

  for (int b = 0; b < 11; ++b) {           // phases kt = 3b, 3b+1, 3b+2 (0..32)
    const int ks = (b * 3 + 3) * 64;
    PHASE(0, 1, ks, 13);
    PHASE(1, 2, ks + 64, 13);
    PHASE(2, 0, ks + 128, 13);
  }
  // tail: phases 33 (P=0), 34 (P=1), 35 (P=2) — no more staging
  PHASE_NS(0, 1, 13);  // outstanding t34+t35=26 -> certifies t34
  PHASE_NS(1, 2, 0);   // outstanding t35=13 -> drain (2 steps old, free)
  READF(fYA, fYB, 2, offAhi, offBhi);
  MF(fXA, fXB);
  MF(fYA, fYB);

  // Epilogue: C/D frag layout col = l&15, row = (l>>4)*4 + reg
  const int lg = (l >> 4) * 4;
  #pragma unroll
  for (int m = 0; m < 7; ++m) {
    const int rowb = m0 + wr * 112 + m * 16 + lg;
    float2 st[4];
    #pragma unroll
    for (int r = 0; r < 4; ++r) st[r] = stats[rowb + r];
    #pragma unroll
    for (int n = 0; n < 6; ++n) {
      const int col = n0 + wn * 96 + n * 16 + lane15;
      const float Gc = G[col];
      const float Bc = Bt[col];
      #pragma unroll
      for (int r = 0; r < 4; ++r) {
        out[(size_t)(rowb + r) * 768 + col] = st[r].x * acc[m][n][r] + st[r].y * Gc + Bc;
      }
    }
  }
#undef STAGE
#undef READF
#undef MF
#undef PHASE
#undef PHASE_NS
}

// ---------------------------------------------------------------------------
// Workspace layout (bytes):
//   V     : 0            57,802,752
//   w2t   : 57,802,752    3,538,944
//   stats : 61,341,696      100,352
//   G     : 61,442,048        3,072
//   Bt    : 61,445,120        3,072
//   Gp    : 61,448,192      442,368
//   Bp    : 61,890,560      442,368   -> total 62,332,928
// ---------------------------------------------------------------------------
extern "C" void kernel_launch(void* const* d_in, const int* in_sizes, int n_in,
                              void* d_out, int out_size, void* d_ws, size_t ws_size,
                              hipStream_t stream) {
  const float* x     = (const float*)d_in[0];
  const float* gamma = (const float*)d_in[1];
  const float* beta  = (const float*)d_in[2];
  const float* w     = (const float*)d_in[3];
  const float* bvec  = (const float*)d_in[4];
  float* out = (float*)d_out;

  char* ws = (char*)d_ws;
  unsigned short* V   = (unsigned short*)(ws);
  unsigned short* w2t = (unsigned short*)(ws + 57802752);
  float2* stats       = (float2*)(ws + 61341696);
  float* G            = (float*)(ws + 61442048);
  float* Bt           = (float*)(ws + 61445120);
  float* Gp           = (float*)(ws + 61448192);
  float* Bp           = (float*)(ws + 61890560);

  spt_pack<<<896, 256, 0, stream>>>(x, V, stats);
  spt_fold_w<<<dim3(144, 3), 256, 0, stream>>>(gamma, beta, w, w2t, Gp, Bp);
  spt_gb<<<3, 256, 0, stream>>>(Gp, Bp, bvec, G, Bt);
  spt_gemm<<<224, 256, 0, stream>>>(V, w2t, stats, G, Bt, out);
}

// Round 9
// 98.694 us; speedup vs baseline: 1.2955x; 1.0880x over previous
//
#include <hip/hip_runtime.h>

// ShiftedPatchTokenization on MI355X (gfx950)
// x[64,3,224,224] f32 -> out[64,196,768] f32
// fold_w (+G/Bt partials) -> gb reduce -> pack (512thr vec4) -> 224x96 dbuf
// MFMA GEMM with co-resident-block anti-phase stagger (s_sleep).

typedef short bf16x8 __attribute__((ext_vector_type(8)));
typedef unsigned short u16x8 __attribute__((ext_vector_type(8)));
typedef float f32x4 __attribute__((ext_vector_type(4)));

#define GLOBAL_AS __attribute__((address_space(1)))
#define LDS_AS __attribute__((address_space(3)))

__device__ __forceinline__ unsigned short f2bf(float f) {
  union { float f; unsigned int u; } v;
  v.f = f;
  unsigned int u = v.u;
  unsigned int r = (u + 0x7FFFu + ((u >> 16) & 1u)) >> 16;  // RNE
  return (unsigned short)r;
}

// ---------------------------------------------------------------------------
// Kernel 1: fold gamma*w over duplicated shift groups -> w2t[768][2304] bf16,
// plus per-f2-block partial sums. grid (144, 3), block 256
// ---------------------------------------------------------------------------
__global__ __launch_bounds__(256) void spt_fold_w(
    const float* __restrict__ gamma, const float* __restrict__ beta,
    const float* __restrict__ w, unsigned short* __restrict__ w2t,
    float* __restrict__ Gp, float* __restrict__ Bp)
{
  __shared__ float tile[16][257];
  const int f2blk = blockIdx.x * 16;
  const int jblk  = blockIdx.y * 256;
  const int t = threadIdx.x;
  const int j = jblk + t;
  float gacc = 0.f, bacc = 0.f;
  #pragma unroll
  for (int i = 0; i < 16; ++i) {
    const int f2 = f2blk + i;
    const int g = f2 / 768;
    const int rem = f2 % 768;  // c*256 + p1*16 + p2
    float v, bv;
    if (g == 0) {
      const int f = rem;
      const float wv = w[(size_t)f * 768 + j];
      v = gamma[f] * wv;
      bv = beta[f] * wv;
    } else if (g == 1) {
      const int fa = 768 + rem, fb = 2304 + rem;   // left_up, left_down
      const float wa = w[(size_t)fa * 768 + j], wb = w[(size_t)fb * 768 + j];
      v = gamma[fa] * wa + gamma[fb] * wb;
      bv = beta[fa] * wa + beta[fb] * wb;
    } else {
      const int fa = 1536 + rem, fb = 3072 + rem;  // right_up, right_down
      const float wa = w[(size_t)fa * 768 + j], wb = w[(size_t)fb * 768 + j];
      v = gamma[fa] * wa + gamma[fb] * wb;
      bv = beta[fa] * wa + beta[fb] * wb;
    }
    tile[i][t] = v;
    gacc += v;
    bacc += bv;
  }
  __syncthreads();
  u16x8 lo, hi;
  #pragma unroll
  for (int i = 0; i < 8; ++i) {
    lo[i] = f2bf(tile[i][t]);
    hi[i] = f2bf(tile[8 + i][t]);
  }
  unsigned short* dst = w2t + (size_t)j * 2304 + f2blk;
  *(u16x8*)dst = lo;
  *(u16x8*)(dst + 8) = hi;
  Gp[blockIdx.x * 768 + j] = gacc;
  Bp[blockIdx.x * 768 + j] = bacc;
}

// ---------------------------------------------------------------------------
// Kernel 2: reduce 144 partials -> G[768], Bt[768] (+b). grid 3, block 256
// ---------------------------------------------------------------------------
__global__ __launch_bounds__(256) void spt_gb(
    const float* __restrict__ Gp, const float* __restrict__ Bp,
    const float* __restrict__ bvec, float* __restrict__ G, float* __restrict__ Bt)
{
  const int j = blockIdx.x * 256 + threadIdx.x;
  float g = 0.f, bb = 0.f;
  for (int i = 0; i < 144; ++i) {
    g += Gp[i * 768 + j];
    bb += Bp[i * 768 + j];
  }
  G[j] = g;
  Bt[j] = bb + bvec[j];
}

// ---------------------------------------------------------------------------
// Kernel 3: pack V[12544][2304] bf16 + per-token LN stats (r, -mu*r)
// 512 threads: 8 groups x 56 x-quads, 6 serial (c,p1) iters each (was 4x12)
// -> half the latency chain, 16 waves/CU. grid 896.
// ---------------------------------------------------------------------------
__global__ __launch_bounds__(512) void spt_pack(
    const float* __restrict__ x, unsigned short* __restrict__ V,
    float2* __restrict__ stats)
{
  __shared__ unsigned short slab[14 * 2312];  // token-major, +8 pad per row
  __shared__ float sred[8][224];
  __shared__ float qred[8][224];
  const int bi = blockIdx.x;
  const int b = bi / 14, hi = bi % 14;
  const int t = threadIdx.x;
  const float TW = 16.0f / 224.0f;

  const int q = t % 56;
  const int grp = t / 56;     // 0..9; active grp<8
  const int x4 = q * 4;

  int sloff[4];
  {
    int wi = x4 % 14, p2 = x4 / 14;
    #pragma unroll
    for (int j = 0; j < 4; ++j) {
      sloff[j] = wi * 2312 + p2;
      if (++wi == 14) { wi = 0; ++p2; }
    }
  }

  if (grp < 8) {
    f32x4 sAcc = {0.f, 0.f, 0.f, 0.f}, qAcc = {0.f, 0.f, 0.f, 0.f};
    #pragma unroll
    for (int it = 0; it < 6; ++it) {
      const int cp = grp * 6 + it;
      const int c = cp >> 4, p1 = cp & 15;
      const int y = p1 * 14 + hi;
      const float* row = x + ((size_t)(b * 3 + c)) * 50176 + (size_t)y * 224;
      const f32x4 xv = *(const f32x4*)(row + x4);
      f32x4 ra = {0.f,0.f,0.f,0.f}, rb = {0.f,0.f,0.f,0.f};
      f32x4 la = {0.f,0.f,0.f,0.f}, lb = {0.f,0.f,0.f,0.f};
      if (q < 54) {
        ra = *(const f32x4*)(row + x4 + 8);
        if (y < 223) rb = *(const f32x4*)(row + x4 + 8 + 224);
      }
      if (q >= 2) {
        la = *(const f32x4*)(row + x4 - 8);
        if (y > 0) lb = *(const f32x4*)(row + x4 - 8 - 224);
      }
      const f32x4 rv = (1.0f - TW) * ra + TW * rb;
      const f32x4 lv = (1.0f - TW) * la + TW * lb;
      sAcc += xv + 2.0f * (lv + rv);
      qAcc += xv * xv + 2.0f * (lv * lv + rv * rv);
      const int kb = c * 256 + p1 * 16;
      #pragma unroll
      for (int j = 0; j < 4; ++j) {
        slab[sloff[j] + kb]        = f2bf(xv[j]);
        slab[sloff[j] + kb + 768]  = f2bf(lv[j]);
        slab[sloff[j] + kb + 1536] = f2bf(rv[j]);
      }
    }
    #pragma unroll
    for (int j = 0; j < 4; ++j) {
      sred[grp][x4 + j] = sAcc[j];
      qred[grp][x4 + j] = qAcc[j];
    }
  }
  __syncthreads();

  if (t < 224) {
    float ss = 0.f, qq = 0.f;
    #pragma unroll
    for (int g = 0; g < 8; ++g) { ss += sred[g][t]; qq += qred[g][t]; }
    sred[0][t] = ss;  // column-private: each thread reads/writes only col t
    qred[0][t] = qq;
  }
  __syncthreads();

  const int tok0 = b * 196 + hi * 14;
  if (t < 14) {
    float S = 0.f, Q = 0.f;
    #pragma unroll
    for (int p = 0; p < 16; ++p) { S += sred[0][t + 14 * p]; Q += qred[0][t + 14 * p]; }
    const float mu = S / 3840.f;
    const float var = Q / 3840.f - mu * mu;
    const float r = rsqrtf(var + 1e-5f);
    stats[tok0 + t] = make_float2(r, -mu * r);
  }

  for (int i = t; i < 14 * 288; i += 512) {
    const int wi2 = i / 288, off = i % 288;
    *(u16x8*)&V[(size_t)(tok0 + wi2) * 2304 + off * 8] =
        *(const u16x8*)&slab[wi2 * 2312 + off * 8];
  }
}

// ---------------------------------------------------------------------------
// Kernel 4: GEMM  out[m][j] = r_m * (V[m,:] . w2t[j,:]) + (-mu*r)_m * G[j] + Bt[j]
// 224x96 tile, BK=64, 4 waves (2x2, wave 112x48), dbuf 80 KiB -> 2 blocks/CU.
// Counted vmcnt(10), raw s_barrier, XOR swizzle, hoisted frags + setprio burst.
// NEW: co-resident-block anti-phase stagger. The two blocks on a CU are
// phase-correlated (same code, same start) -> LDS read phases and MFMA bursts
// collide instead of overlapping (measured: wall = LDS + MFMA serialized).
// One ~830cyc s_sleep on one member of each pair anti-phases them; robust to
// breadth-first (pairs b,b+256) and depth-first (pairs 2k,2k+1) dispatch.
// grid 448 = 56m x 8n, exact XCD swizzle, N-fastest.
// ---------------------------------------------------------------------------
__global__ __launch_bounds__(256, 2) void spt_gemm(
    const unsigned short* __restrict__ V, const unsigned short* __restrict__ w2t,
    const float2* __restrict__ stats, const float* __restrict__ G,
    const float* __restrict__ Bt, float* __restrict__ out)
{
  __shared__ unsigned short Alds[2][224 * 64];
  __shared__ unsigned short Blds[2][96 * 64];

  const int orig = blockIdx.x;
  const int wgid = (orig & 7) * 56 + (orig >> 3);  // exact: 448 = 8 * 56
  const int m0 = (wgid >> 3) * 224;
  const int n0 = (wgid & 7) * 96;

  // anti-phase stagger: pair members differ by 13 sleep units (~830 cyc)
  // under either dispatch pairing scheme.
  if (orig & 1)   asm volatile("s_sleep 13" ::: "memory");
  if (orig & 256) asm volatile("s_sleep 13" ::: "memory");

  const int t = threadIdx.x;
  const int w = t >> 6, l = t & 63;
  const int wr = w >> 1;   // 0..1 -> 112-row half
  const int wn = w & 1;    // 0..1 -> 48-col slice

  f32x4 acc[7][3] = {};

#define STAGE(pb, kt)                                                          \
  {                                                                            \
    const int k0s = (kt) << 6;                                                 \
    _Pragma("unroll") for (int i = 0; i < 7; ++i) {                            \
      const int c = i * 256 + t;                                               \
      const int row = c >> 3;                                                  \
      const int srcel = (((c & 7) ^ (row & 7)) << 3);                          \
      const unsigned short* ga = V + (size_t)(m0 + row) * 2304 + k0s + srcel;  \
      __builtin_amdgcn_global_load_lds((const GLOBAL_AS unsigned int*)ga,      \
          (LDS_AS unsigned int*)&Alds[pb][i * 2048 + w * 512], 16, 0, 0);      \
    }                                                                          \
    _Pragma("unroll") for (int i = 0; i < 3; ++i) {                            \
      const int c = i * 256 + t;                                               \
      const int row = c >> 3;                                                  \
      const int srcel = (((c & 7) ^ (row & 7)) << 3);                          \
      const unsigned short* gb = w2t + (size_t)(n0 + row) * 2304 + k0s + srcel;\
      __builtin_amdgcn_global_load_lds((const GLOBAL_AS unsigned int*)gb,      \
          (LDS_AS unsigned int*)&Blds[pb][i * 2048 + w * 512], 16, 0, 0);      \
    }                                                                          \
  }

  // Load ALL fragments of the K-step into registers, then a pure-register
  // MFMA burst under raised priority (clean read-phase / burst-phase split
  // so anti-phased co-resident blocks interleave pipes).
#define COMPUTE(pb)                                                            \
  {                                                                            \
    const int lane15 = l & 15;                                                 \
    const int kcol = (l >> 4) << 4;                                            \
    bf16x8 bF[2][3], aF[2][7];                                                 \
    _Pragma("unroll") for (int kk = 0; kk < 2; ++kk) {                         \
      const int kb = kk * 64 + kcol;                                           \
      _Pragma("unroll") for (int n = 0; n < 3; ++n) {                          \
        const int row = wn * 48 + n * 16 + lane15;                             \
        const int phys = row * 128 + (kb ^ ((row & 7) << 4));                  \
        bF[kk][n] = *(const bf16x8*)&Blds[pb][phys >> 1];                      \
      }                                                                        \
      _Pragma("unroll") for (int m = 0; m < 7; ++m) {                          \
        const int row = wr * 112 + m * 16 + lane15;                            \
        const int phys = row * 128 + (kb ^ ((row & 7) << 4));                  \
        aF[kk][m] = *(const bf16x8*)&Alds[pb][phys >> 1];                      \
      }                                                                        \
    }                                                                          \
    __builtin_amdgcn_s_setprio(1);                                             \
    _Pragma("unroll") for (int kk = 0; kk < 2; ++kk)                           \
      _Pragma("unroll") for (int m = 0; m < 7; ++m)                            \
        _Pragma("unroll") for (int n = 0; n < 3; ++n)                          \
          acc[m][n] = __builtin_amdgcn_mfma_f32_16x16x32_bf16(aF[kk][m],       \
                          bF[kk][n], acc[m][n], 0, 0, 0);                      \
    __builtin_amdgcn_s_setprio(0);                                             \
  }

  STAGE(0, 0);
  int pb = 0;
  for (int kt = 0; kt < 35; ++kt) {
    STAGE(pb ^ 1, kt + 1);
    // wait for the 10 oldest loads (step kt); 10 newest (kt+1) stay in flight
    asm volatile("s_waitcnt vmcnt(10)\n\ts_barrier" ::: "memory");
    COMPUTE(pb);
    asm volatile("s_barrier" ::: "memory");  // reads of buf pb done before restage
    pb ^= 1;
  }
  asm volatile("s_waitcnt vmcnt(0)\n\ts_barrier" ::: "memory");
  COMPUTE(pb);

  // Epilogue: C/D frag layout col = l&15, row = (l>>4)*4 + reg
  const int lane15 = l & 15;
  const int lg = (l >> 4) * 4;
  #pragma unroll
  for (int m = 0; m < 7; ++m) {
    const int rowb = m0 + wr * 112 + m * 16 + lg;
    float2 st[4];
    #pragma unroll
    for (int r = 0; r < 4; ++r) st[r] = stats[rowb + r];
    #pragma unroll
    for (int n = 0; n < 3; ++n) {
      const int col = n0 + wn * 48 + n * 16 + lane15;
      const float Gc = G[col];
      const float Bc = Bt[col];
      #pragma unroll
      for (int r = 0; r < 4; ++r) {
        out[(size_t)(rowb + r) * 768 + col] = st[r].x * acc[m][n][r] + st[r].y * Gc + Bc;
      }
    }
  }
#undef STAGE
#undef COMPUTE
}

// ---------------------------------------------------------------------------
// Workspace layout (bytes):
//   V     : 0            57,802,752
//   w2t   : 57,802,752    3,538,944
//   stats : 61,341,696      100,352
//   G     : 61,442,048        3,072
//   Bt    : 61,445,120        3,072
//   Gp    : 61,448,192      442,368
//   Bp    : 61,890,560      442,368   -> total 62,332,928
// ---------------------------------------------------------------------------
extern "C" void kernel_launch(void* const* d_in, const int* in_sizes, int n_in,
                              void* d_out, int out_size, void* d_ws, size_t ws_size,
                              hipStream_t stream) {
  const float* x     = (const float*)d_in[0];
  const float* gamma = (const float*)d_in[1];
  const float* beta  = (const float*)d_in[2];
  const float* w     = (const float*)d_in[3];
  const float* bvec  = (const float*)d_in[4];
  float* out = (float*)d_out;

  char* ws = (char*)d_ws;
  unsigned short* V   = (unsigned short*)(ws);
  unsigned short* w2t = (unsigned short*)(ws + 57802752);
  float2* stats       = (float2*)(ws + 61341696);
  float* G            = (float*)(ws + 61442048);
  float* Bt           = (float*)(ws + 61445120);
  float* Gp           = (float*)(ws + 61448192);
  float* Bp           = (float*)(ws + 61890560);

  spt_pack<<<896, 512, 0, stream>>>(x, V, stats);
  spt_fold_w<<<dim3(144, 3), 256, 0, stream>>>(gamma, beta, w, w2t, Gp, Bp);
  spt_gb<<<3, 256, 0, stream>>>(Gp, Bp, bvec, G, Bt);
  spt_gemm<<<448, 256, 0, stream>>>(V, w2t, stats, G, Bt, out);
}